// Round 1
// baseline (547.750 us; speedup 1.0000x reference)
//
#include <hip/hip_runtime.h>

#define B_ 128
#define F_ 128
#define T_ 512
#define TS 64

// Large finite sentinel instead of INF: survives fast-math, never overflows
// (max legitimate DP value ~1e4, sentinel arithmetic stays ~1e30 << 3.4e38).
#define BIGV 1e30f

// ---------------------------------------------------------------------------
// Kernel 1: cost[b][i][j] = sqrt(max(||x_i||^2 + ||y_j||^2 - 2 x_i.y_j, 0))
// for rows i in [i0, i0+slab). Tiled 64x64, f32 VALU GEMM, LDS-staged.
// grid = (T/64, slab/64, B), block = 256.
// ---------------------------------------------------------------------------
__global__ __launch_bounds__(256) void dtw_cost_kernel(
    const float* __restrict__ x, const float* __restrict__ y,
    float* __restrict__ cost, int i0, int slab)
{
    const int tj  = blockIdx.x;      // column tile 0..7
    const int ti  = blockIdx.y;      // row tile within slab
    const int b   = blockIdx.z;
    const int tid = threadIdx.x;
    const int gi0 = i0 + ti * TS;
    const int gj0 = tj * TS;

    __shared__ __align__(16) float Xs[F_][TS];
    __shared__ __align__(16) float Ys[F_][TS];
    __shared__ float x2s[TS];
    __shared__ float y2s[TS];

    const float* xb = x + (size_t)b * F_ * T_;
    const float* yb = y + (size_t)b * F_ * T_;

    // stage: 128 f-rows x 64 floats each; 256 threads -> 16 f-rows per pass.
    const int fr = tid >> 4;         // 0..15
    const int q  = (tid & 15) * 4;   // 0,4,...,60
#pragma unroll
    for (int p = 0; p < 8; ++p) {
        const int f = p * 16 + fr;
        *(float4*)(&Xs[f][q]) = *(const float4*)(xb + (size_t)f * T_ + gi0 + q);
        *(float4*)(&Ys[f][q]) = *(const float4*)(yb + (size_t)f * T_ + gj0 + q);
    }
    __syncthreads();

    // column squared-norms
    if (tid < 64) {
        float s = 0.f;
#pragma unroll
        for (int f = 0; f < F_; ++f) { const float v = Xs[f][tid]; s += v * v; }
        x2s[tid] = s;
    } else if (tid < 128) {
        const int c = tid - 64;
        float s = 0.f;
#pragma unroll
        for (int f = 0; f < F_; ++f) { const float v = Ys[f][c]; s += v * v; }
        y2s[c] = s;
    }
    __syncthreads();

    // 4x4 micro-tile per thread
    const int tr = tid >> 4;   // 0..15
    const int tc = tid & 15;   // 0..15
    float acc[4][4] = {};
#pragma unroll 8
    for (int k = 0; k < F_; ++k) {
        const float4 xa = *(const float4*)(&Xs[k][tr * 4]);
        const float4 ya = *(const float4*)(&Ys[k][tc * 4]);
        const float xv[4] = {xa.x, xa.y, xa.z, xa.w};
        const float yv[4] = {ya.x, ya.y, ya.z, ya.w};
#pragma unroll
        for (int r = 0; r < 4; ++r)
#pragma unroll
            for (int c = 0; c < 4; ++c)
                acc[r][c] = fmaf(xv[r], yv[c], acc[r][c]);
    }

#pragma unroll
    for (int r = 0; r < 4; ++r) {
        const int rowloc = ti * TS + tr * 4 + r;           // row index within slab
        const float x2v = x2s[tr * 4 + r];
        float4 o;
        o.x = sqrtf(fmaxf(x2v + y2s[tc * 4 + 0] - 2.f * acc[r][0], 0.f));
        o.y = sqrtf(fmaxf(x2v + y2s[tc * 4 + 1] - 2.f * acc[r][1], 0.f));
        o.z = sqrtf(fmaxf(x2v + y2s[tc * 4 + 2] - 2.f * acc[r][2], 0.f));
        o.w = sqrtf(fmaxf(x2v + y2s[tc * 4 + 3] - 2.f * acc[r][3], 0.f));
        *(float4*)(cost + ((size_t)b * slab + rowloc) * T_ + gj0 + tc * 4) = o;
    }
}

// ---------------------------------------------------------------------------
// Kernel 2: DTW DP rows [i0, i1). One 64-lane wave per batch, 8 cols/lane.
// Row recurrence cur[j] = c[j] + min(a[j], cur[j-1]) solved as scan:
//   S = prefix_sum(c); cur[j] = S[j] + min_{k<=j} (a[k] - S[k-1]).
// Frontier row persisted in `state` between slabs (untouched if slab==512).
// ---------------------------------------------------------------------------
__global__ __launch_bounds__(64) void dtw_dp_kernel(
    const float* __restrict__ cost, float* __restrict__ state,
    float* __restrict__ out, int i0, int i1, int slab)
{
    const int b = blockIdx.x;
    const int L = threadIdx.x;          // lane 0..63

    float prev[8];
    if (i0 == 0) {
#pragma unroll
        for (int k = 0; k < 8; ++k) prev[k] = BIGV;
    } else {
        const float4 p0 = *(const float4*)(state + (size_t)b * T_ + L * 8);
        const float4 p1 = *(const float4*)(state + (size_t)b * T_ + L * 8 + 4);
        prev[0] = p0.x; prev[1] = p0.y; prev[2] = p0.z; prev[3] = p0.w;
        prev[4] = p1.x; prev[5] = p1.y; prev[6] = p1.z; prev[7] = p1.w;
    }

    const float* crow = cost + (size_t)b * slab * T_ + L * 8;
    for (int i = i0; i < i1; ++i, crow += T_) {
        const float4 c0 = *(const float4*)(crow);
        const float4 c1 = *(const float4*)(crow + 4);
        const float c[8] = {c0.x, c0.y, c0.z, c0.w, c1.x, c1.y, c1.z, c1.w};

        // per-lane inclusive prefix sum
        float s[8];
        s[0] = c[0];
#pragma unroll
        for (int k = 1; k < 8; ++k) s[k] = s[k - 1] + c[k];

        // wave-inclusive scan of lane totals
        float tot = s[7];
#pragma unroll
        for (int d = 1; d < 64; d <<= 1) {
            const float u = __shfl_up(tot, d);
            if (L >= d) tot += u;
        }
        float exc = __shfl_up(tot, 1);
        if (L == 0) exc = 0.f;

        // a[j] = min(dtw[i-1][j], dtw[i-1][j-1])
        const float pup = __shfl_up(prev[7], 1);
        const float pshift0 = (L == 0) ? ((i == 0) ? 0.f : BIGV) : pup;
        float a[8];
        a[0] = fminf(prev[0], pshift0);
#pragma unroll
        for (int k = 1; k < 8; ++k) a[k] = fminf(prev[k], prev[k - 1]);

        // t[j] = a[j] - S_exclusive[j]; prefix-min of t
        float t[8], m[8];
#pragma unroll
        for (int k = 0; k < 8; ++k) t[k] = a[k] - (exc + (s[k] - c[k]));
        m[0] = t[0];
#pragma unroll
        for (int k = 1; k < 8; ++k) m[k] = fminf(m[k - 1], t[k]);

        float mn = m[7];
#pragma unroll
        for (int d = 1; d < 64; d <<= 1) {
            const float u = __shfl_up(mn, d);
            if (L >= d) mn = fminf(mn, u);
        }
        float mexc = __shfl_up(mn, 1);
        if (L == 0) mexc = BIGV;

#pragma unroll
        for (int k = 0; k < 8; ++k) prev[k] = exc + s[k] + fminf(mexc, m[k]);
    }

    if (i1 == T_) {
        if (L == 63) out[b] = prev[7];
    } else {
        float4 p0, p1;
        p0.x = prev[0]; p0.y = prev[1]; p0.z = prev[2]; p0.w = prev[3];
        p1.x = prev[4]; p1.y = prev[5]; p1.z = prev[6]; p1.w = prev[7];
        *(float4*)(state + (size_t)b * T_ + L * 8) = p0;
        *(float4*)(state + (size_t)b * T_ + L * 8 + 4) = p1;
    }
}

// ---------------------------------------------------------------------------
extern "C" void kernel_launch(void* const* d_in, const int* in_sizes, int n_in,
                              void* d_out, int out_size, void* d_ws, size_t ws_size,
                              hipStream_t stream)
{
    const float* x = (const float*)d_in[0];
    const float* y = (const float*)d_in[1];
    float* out = (float*)d_out;

    const size_t state_bytes = (size_t)B_ * T_ * sizeof(float);
    int slab = 64;
    for (int s = 512; s >= 64; s >>= 1) {
        const size_t need = (size_t)B_ * s * T_ * sizeof(float) +
                            (s == 512 ? 0 : state_bytes);
        if (ws_size >= need) { slab = s; break; }
    }

    float* cost_ws = (float*)d_ws;
    float* state   = (float*)((char*)d_ws + (size_t)B_ * slab * T_ * sizeof(float));

    for (int i0 = 0; i0 < T_; i0 += slab) {
        dim3 grid(T_ / TS, slab / TS, B_);
        hipLaunchKernelGGL(dtw_cost_kernel, grid, dim3(256), 0, stream,
                           x, y, cost_ws, i0, slab);
        hipLaunchKernelGGL(dtw_dp_kernel, dim3(B_), dim3(64), 0, stream,
                           cost_ws, state, out, i0, i0 + slab, slab);
    }
}